// Round 3
// baseline (8856.577 us; speedup 1.0000x reference)
//
#include <hip/hip_runtime.h>
#include <math.h>

// InteractingLayer (AutoInt): B=4096, F=50, E=64, H=4, D=32.
// One block per batch row b; 4 heads sequential so X[b] is staged once.
// fp32 baseline (no fp32 MFMA on CDNA4 -> VALU-bound, ~119us ideal).
//
// LDS float map (11904 floats = 47616 B, 3 blocks/CU):
//   Region A floats [0, 8704):
//     proj phase:   Wt[m][d][e] at m*2176 + d*68 + e   (pad 68: b128 reads at bank floor)
//     post-proj:    Ss[50][52] at 0      (cols 50..51 zeroed for float4 PV)
//                   Qs[50][34] at 2600   (pad 34: float2, bank stride 2 = free)
//                   Ks[50][34] at 4300
//                   Vt[32][52] at 6000   (V transposed, cols 50..51 zeroed)
//   Region B floats [8704, 11904): Xs[50][64], persistent across heads.

namespace {

constexpr int kB = 4096;
constexpr int kF = 50;
constexpr int kE = 64;
constexpr int kD = 32;
constexpr int kH = 4;

__device__ __forceinline__ void dot4(float& acc, const float4& a, const float4& b) {
  acc = fmaf(a.x, b.x, fmaf(a.y, b.y, fmaf(a.z, b.z, fmaf(a.w, b.w, acc))));
}

__global__ __launch_bounds__(256, 3)
void interacting_layer_kernel(const float* __restrict__ x,
                              const float* __restrict__ Wq,
                              const float* __restrict__ Wk,
                              const float* __restrict__ Wv,
                              const float* __restrict__ Wr,
                              float* __restrict__ out)
{
  const int tid = threadIdx.x;
  const int b   = blockIdx.x;

  __shared__ __align__(16) float SM[11904];
  float* XS = SM + 8704;

  // ---- stage X[b] (50x64 fp32) once, float4-coalesced ----
  {
    const float4* xg = reinterpret_cast<const float4*>(x + (size_t)b * (kF * kE));
    float4* xs = reinterpret_cast<float4*>(XS);
    #pragma unroll
    for (int it = 0; it < 4; ++it) {
      int idx = tid + it * 256;
      if (idx < (kF * kE / 4)) xs[idx] = xg[idx];   // 800 float4
    }
  }

  const int dl = tid & 31;   // output column within head (d)
  const int f2 = tid >> 5;   // row group 0..7; thread owns rows f2+8*i, i<7

  for (int h = 0; h < kH; ++h) {
    __syncthreads();  // prev head's PV reads of region A done (no-op cost at h==0)

    // ---- stage W slices for head h, transposed: Wt[m][d][e] ----
    {
      int i = tid;
      #pragma unroll
      for (int it = 0; it < 2; ++it, i += 256) {    // 512 float4-groups total
        int e  = i >> 3;          // 0..63
        int d4 = (i & 7) << 2;    // 0,4,...,28
        int g  = e * 128 + h * 32 + d4;             // W[e][h*32 + d4 .. +3]
        float4 q4 = *reinterpret_cast<const float4*>(Wq + g);
        float4 k4 = *reinterpret_cast<const float4*>(Wk + g);
        float4 v4 = *reinterpret_cast<const float4*>(Wv + g);
        float4 r4 = *reinterpret_cast<const float4*>(Wr + g);
        SM[0*2176 + (d4+0)*68 + e] = q4.x;
        SM[0*2176 + (d4+1)*68 + e] = q4.y;
        SM[0*2176 + (d4+2)*68 + e] = q4.z;
        SM[0*2176 + (d4+3)*68 + e] = q4.w;
        SM[1*2176 + (d4+0)*68 + e] = k4.x;
        SM[1*2176 + (d4+1)*68 + e] = k4.y;
        SM[1*2176 + (d4+2)*68 + e] = k4.z;
        SM[1*2176 + (d4+3)*68 + e] = k4.w;
        SM[2*2176 + (d4+0)*68 + e] = v4.x;
        SM[2*2176 + (d4+1)*68 + e] = v4.y;
        SM[2*2176 + (d4+2)*68 + e] = v4.z;
        SM[2*2176 + (d4+3)*68 + e] = v4.w;
        SM[3*2176 + (d4+0)*68 + e] = r4.x;
        SM[3*2176 + (d4+1)*68 + e] = r4.y;
        SM[3*2176 + (d4+2)*68 + e] = r4.z;
        SM[3*2176 + (d4+3)*68 + e] = r4.w;
      }
    }
    __syncthreads();  // W staged (and X staged for h==0)

    // ---- projections: thread computes rows f2+8*i (i<7), column dl ----
    float aQ[7], aK[7], aV[7], aR[7];
    #pragma unroll
    for (int i = 0; i < 7; ++i) { aQ[i] = 0.f; aK[i] = 0.f; aV[i] = 0.f; aR[i] = 0.f; }
    const float* wqp = SM + 0*2176 + dl*68;
    const float* wkp = SM + 1*2176 + dl*68;
    const float* wvp = SM + 2*2176 + dl*68;
    const float* wrp = SM + 3*2176 + dl*68;
    #pragma unroll
    for (int ec = 0; ec < 16; ++ec) {
      float4 wq4 = *reinterpret_cast<const float4*>(wqp + ec*4);
      float4 wk4 = *reinterpret_cast<const float4*>(wkp + ec*4);
      float4 wv4 = *reinterpret_cast<const float4*>(wvp + ec*4);
      float4 wr4 = *reinterpret_cast<const float4*>(wrp + ec*4);
      #pragma unroll
      for (int i = 0; i < 7; ++i) {
        int f = f2 + 8*i; if (f > kF-1) f = kF-1;  // clamp: rows >=50 discarded at write
        float4 x4 = *reinterpret_cast<const float4*>(XS + f*64 + ec*4);
        dot4(aQ[i], x4, wq4);
        dot4(aK[i], x4, wk4);
        dot4(aV[i], x4, wv4);
        dot4(aR[i], x4, wr4);
      }
    }
    __syncthreads();  // all reads of Wt done; region A may be overwritten

    // ---- write Q, K (row-major pad 34), V transposed (pad 52); zero pads ----
    #pragma unroll
    for (int i = 0; i < 7; ++i) {
      int f = f2 + 8*i;
      if (f < kF) {
        SM[2600 + f*34 + dl] = aQ[i];
        SM[4300 + f*34 + dl] = aK[i];
        SM[6000 + dl*52 + f] = aV[i];
      }
    }
    if (tid < 64)  SM[6000 + (tid >> 1)*52 + 50 + (tid & 1)] = 0.f;  // Vt[:,50:52]=0
    if (tid < 100) SM[(tid >> 1)*52 + 50 + (tid & 1)] = 0.f;         // Ss[:,50:52]=0
    __syncthreads();

    // ---- scores: s[f][g] = sum_d Q[f][d]*K[g][d] (unscaled) ----
    for (int i = tid; i < kF * kF; i += 256) {
      int f = i / 50;
      int g = i - f * 50;
      const float2* q2 = reinterpret_cast<const float2*>(SM + 2600 + f*34);
      const float2* k2 = reinterpret_cast<const float2*>(SM + 4300 + g*34);
      float s = 0.f;
      #pragma unroll
      for (int c = 0; c < 16; ++c) {
        float2 qa = q2[c];
        float2 ka = k2[c];
        s = fmaf(qa.x, ka.x, s);
        s = fmaf(qa.y, ka.y, s);
      }
      SM[f*52 + g] = s;
    }
    __syncthreads();

    // ---- softmax over g, 4 lanes per row (rows in lanes, 13 g per lane) ----
    if (tid < 200) {
      int f   = tid >> 2;      // 0..49
      int sub = tid & 3;
      float m = -1e30f;
      #pragma unroll
      for (int j = 0; j < 13; ++j) {
        int g = sub + 4*j;
        if (g < kF) m = fmaxf(m, SM[f*52 + g]);
      }
      m = fmaxf(m, __shfl_xor(m, 1));
      m = fmaxf(m, __shfl_xor(m, 2));
      float ev[13];
      float s = 0.f;
      #pragma unroll
      for (int j = 0; j < 13; ++j) {
        int g = sub + 4*j;
        if (g < kF) { ev[j] = __expf(SM[f*52 + g] - m); s += ev[j]; }
      }
      s += __shfl_xor(s, 1);
      s += __shfl_xor(s, 2);
      float inv = 1.f / s;
      #pragma unroll
      for (int j = 0; j < 13; ++j) {
        int g = sub + 4*j;
        if (g < kF) SM[f*52 + g] = ev[j] * inv;
      }
    }
    __syncthreads();

    // ---- PV + residual + ReLU + store ----
    float acc[7];
    #pragma unroll
    for (int i = 0; i < 7; ++i) acc[i] = aR[i];  // residual X@Wr from proj phase
    const float4* vt = reinterpret_cast<const float4*>(SM + 6000 + dl*52);
    #pragma unroll
    for (int gc = 0; gc < 13; ++gc) {
      float4 v4 = vt[gc];                        // V^T[dl][4g..], cols>=50 are zero
      #pragma unroll
      for (int i = 0; i < 7; ++i) {
        int f = f2 + 8*i; if (f > kF-1) f = kF-1;
        float4 s4 = *reinterpret_cast<const float4*>(SM + f*52 + gc*4);
        dot4(acc[i], s4, v4);
      }
    }
    float* ob = out + (size_t)b * (kF * 128) + h*32 + dl;
    #pragma unroll
    for (int i = 0; i < 7; ++i) {
      int f = f2 + 8*i;
      if (f < kF) ob[f*128] = fmaxf(acc[i], 0.f);
    }
  }
}

}  // namespace

extern "C" void kernel_launch(void* const* d_in, const int* in_sizes, int n_in,
                              void* d_out, int out_size, void* d_ws, size_t ws_size,
                              hipStream_t stream) {
  const float* x  = (const float*)d_in[0];
  const float* wq = (const float*)d_in[1];
  const float* wk = (const float*)d_in[2];
  const float* wv = (const float*)d_in[3];
  const float* wr = (const float*)d_in[4];
  float* outp = (float*)d_out;
  (void)in_sizes; (void)n_in; (void)d_ws; (void)ws_size; (void)out_size;
  hipLaunchKernelGGL(interacting_layer_kernel, dim3(kB), dim3(256), 0, stream,
                     x, wq, wk, wv, wr, outp);
}

// Round 5
// 7534.338 us; speedup vs baseline: 1.1755x; 1.1755x over previous
//
#include <hip/hip_runtime.h>
#include <math.h>

// InteractingLayer (AutoInt): B=4096, F=50, E=64, H=4, D=32.
// One block per batch row b; 4 heads sequential so X[b] is staged once.
// fp32 path (no fp32 MFMA on CDNA4).
//
// R4 change vs R3: __launch_bounds__(256, 3) -> (256, 2).
// R3 evidence: VGPR_Count=84 (= allocator cap for 3 waves/EU), FETCH+WRITE
// = 28.6 GB symmetric (scratch spill/fill of the proj accumulator arrays),
// VALUBusy 3.6%, dur 8.8 ms. LDS (47.6 KB) caps residency at 3 blocks/CU
// anyway, so relaxing the VGPR cap costs no occupancy.
//
// LDS float map (11904 floats = 47616 B, 3 blocks/CU):
//   Region A floats [0, 8704):
//     proj phase:   Wt[m][d][e] at m*2176 + d*68 + e   (pad 68: b128 reads at bank floor)
//     post-proj:    Ss[50][52] at 0      (cols 50..51 zeroed for float4 PV)
//                   Qs[50][34] at 2600   (pad 34: float2, bank stride 2 = free)
//                   Ks[50][34] at 4300
//                   Vt[32][52] at 6000   (V transposed, cols 50..51 zeroed)
//   Region B floats [8704, 11904): Xs[50][64], persistent across heads.

namespace {

constexpr int kB = 4096;
constexpr int kF = 50;
constexpr int kE = 64;
constexpr int kD = 32;
constexpr int kH = 4;

__device__ __forceinline__ void dot4(float& acc, const float4& a, const float4& b) {
  acc = fmaf(a.x, b.x, fmaf(a.y, b.y, fmaf(a.z, b.z, fmaf(a.w, b.w, acc))));
}

__global__ __launch_bounds__(256, 2)
void interacting_layer_kernel(const float* __restrict__ x,
                              const float* __restrict__ Wq,
                              const float* __restrict__ Wk,
                              const float* __restrict__ Wv,
                              const float* __restrict__ Wr,
                              float* __restrict__ out)
{
  const int tid = threadIdx.x;
  const int b   = blockIdx.x;

  __shared__ __align__(16) float SM[11904];
  float* XS = SM + 8704;

  // ---- stage X[b] (50x64 fp32) once, float4-coalesced ----
  {
    const float4* xg = reinterpret_cast<const float4*>(x + (size_t)b * (kF * kE));
    float4* xs = reinterpret_cast<float4*>(XS);
    #pragma unroll
    for (int it = 0; it < 4; ++it) {
      int idx = tid + it * 256;
      if (idx < (kF * kE / 4)) xs[idx] = xg[idx];   // 800 float4
    }
  }

  const int dl = tid & 31;   // output column within head (d)
  const int f2 = tid >> 5;   // row group 0..7; thread owns rows f2+8*i, i<7

  for (int h = 0; h < kH; ++h) {
    __syncthreads();  // prev head's PV reads of region A done (no-op cost at h==0)

    // ---- stage W slices for head h, transposed: Wt[m][d][e] ----
    {
      int i = tid;
      #pragma unroll
      for (int it = 0; it < 2; ++it, i += 256) {    // 512 float4-groups total
        int e  = i >> 3;          // 0..63
        int d4 = (i & 7) << 2;    // 0,4,...,28
        int g  = e * 128 + h * 32 + d4;             // W[e][h*32 + d4 .. +3]
        float4 q4 = *reinterpret_cast<const float4*>(Wq + g);
        float4 k4 = *reinterpret_cast<const float4*>(Wk + g);
        float4 v4 = *reinterpret_cast<const float4*>(Wv + g);
        float4 r4 = *reinterpret_cast<const float4*>(Wr + g);
        SM[0*2176 + (d4+0)*68 + e] = q4.x;
        SM[0*2176 + (d4+1)*68 + e] = q4.y;
        SM[0*2176 + (d4+2)*68 + e] = q4.z;
        SM[0*2176 + (d4+3)*68 + e] = q4.w;
        SM[1*2176 + (d4+0)*68 + e] = k4.x;
        SM[1*2176 + (d4+1)*68 + e] = k4.y;
        SM[1*2176 + (d4+2)*68 + e] = k4.z;
        SM[1*2176 + (d4+3)*68 + e] = k4.w;
        SM[2*2176 + (d4+0)*68 + e] = v4.x;
        SM[2*2176 + (d4+1)*68 + e] = v4.y;
        SM[2*2176 + (d4+2)*68 + e] = v4.z;
        SM[2*2176 + (d4+3)*68 + e] = v4.w;
        SM[3*2176 + (d4+0)*68 + e] = r4.x;
        SM[3*2176 + (d4+1)*68 + e] = r4.y;
        SM[3*2176 + (d4+2)*68 + e] = r4.z;
        SM[3*2176 + (d4+3)*68 + e] = r4.w;
      }
    }
    __syncthreads();  // W staged (and X staged for h==0)

    // ---- projections: thread computes rows f2+8*i (i<7), column dl ----
    float aQ[7], aK[7], aV[7], aR[7];
    #pragma unroll
    for (int i = 0; i < 7; ++i) { aQ[i] = 0.f; aK[i] = 0.f; aV[i] = 0.f; aR[i] = 0.f; }
    const float* wqp = SM + 0*2176 + dl*68;
    const float* wkp = SM + 1*2176 + dl*68;
    const float* wvp = SM + 2*2176 + dl*68;
    const float* wrp = SM + 3*2176 + dl*68;
    #pragma unroll
    for (int ec = 0; ec < 16; ++ec) {
      float4 wq4 = *reinterpret_cast<const float4*>(wqp + ec*4);
      float4 wk4 = *reinterpret_cast<const float4*>(wkp + ec*4);
      float4 wv4 = *reinterpret_cast<const float4*>(wvp + ec*4);
      float4 wr4 = *reinterpret_cast<const float4*>(wrp + ec*4);
      #pragma unroll
      for (int i = 0; i < 7; ++i) {
        int f = f2 + 8*i; if (f > kF-1) f = kF-1;  // clamp: rows >=50 discarded at write
        float4 x4 = *reinterpret_cast<const float4*>(XS + f*64 + ec*4);
        dot4(aQ[i], x4, wq4);
        dot4(aK[i], x4, wk4);
        dot4(aV[i], x4, wv4);
        dot4(aR[i], x4, wr4);
      }
    }
    __syncthreads();  // all reads of Wt done; region A may be overwritten

    // ---- write Q, K (row-major pad 34), V transposed (pad 52); zero pads ----
    #pragma unroll
    for (int i = 0; i < 7; ++i) {
      int f = f2 + 8*i;
      if (f < kF) {
        SM[2600 + f*34 + dl] = aQ[i];
        SM[4300 + f*34 + dl] = aK[i];
        SM[6000 + dl*52 + f] = aV[i];
      }
    }
    if (tid < 64)  SM[6000 + (tid >> 1)*52 + 50 + (tid & 1)] = 0.f;  // Vt[:,50:52]=0
    if (tid < 100) SM[(tid >> 1)*52 + 50 + (tid & 1)] = 0.f;         // Ss[:,50:52]=0
    __syncthreads();

    // ---- scores: s[f][g] = sum_d Q[f][d]*K[g][d] (unscaled) ----
    for (int i = tid; i < kF * kF; i += 256) {
      int f = i / 50;
      int g = i - f * 50;
      const float2* q2 = reinterpret_cast<const float2*>(SM + 2600 + f*34);
      const float2* k2 = reinterpret_cast<const float2*>(SM + 4300 + g*34);
      float s = 0.f;
      #pragma unroll
      for (int c = 0; c < 16; ++c) {
        float2 qa = q2[c];
        float2 ka = k2[c];
        s = fmaf(qa.x, ka.x, s);
        s = fmaf(qa.y, ka.y, s);
      }
      SM[f*52 + g] = s;
    }
    __syncthreads();

    // ---- softmax over g, 4 lanes per row (rows in lanes, 13 g per lane) ----
    if (tid < 200) {
      int f   = tid >> 2;      // 0..49
      int sub = tid & 3;
      float m = -1e30f;
      #pragma unroll
      for (int j = 0; j < 13; ++j) {
        int g = sub + 4*j;
        if (g < kF) m = fmaxf(m, SM[f*52 + g]);
      }
      m = fmaxf(m, __shfl_xor(m, 1));
      m = fmaxf(m, __shfl_xor(m, 2));
      float ev[13];
      float s = 0.f;
      #pragma unroll
      for (int j = 0; j < 13; ++j) {
        int g = sub + 4*j;
        if (g < kF) { ev[j] = __expf(SM[f*52 + g] - m); s += ev[j]; }
      }
      s += __shfl_xor(s, 1);
      s += __shfl_xor(s, 2);
      float inv = 1.f / s;
      #pragma unroll
      for (int j = 0; j < 13; ++j) {
        int g = sub + 4*j;
        if (g < kF) SM[f*52 + g] = ev[j] * inv;
      }
    }
    __syncthreads();

    // ---- PV + residual + ReLU + store ----
    float acc[7];
    #pragma unroll
    for (int i = 0; i < 7; ++i) acc[i] = aR[i];  // residual X@Wr from proj phase
    const float4* vt = reinterpret_cast<const float4*>(SM + 6000 + dl*52);
    #pragma unroll
    for (int gc = 0; gc < 13; ++gc) {
      float4 v4 = vt[gc];                        // V^T[dl][4g..], cols>=50 are zero
      #pragma unroll
      for (int i = 0; i < 7; ++i) {
        int f = f2 + 8*i; if (f > kF-1) f = kF-1;
        float4 s4 = *reinterpret_cast<const float4*>(SM + f*52 + gc*4);
        dot4(acc[i], s4, v4);
      }
    }
    float* ob = out + (size_t)b * (kF * 128) + h*32 + dl;
    #pragma unroll
    for (int i = 0; i < 7; ++i) {
      int f = f2 + 8*i;
      if (f < kF) ob[f*128] = fmaxf(acc[i], 0.f);
    }
  }
}

}  // namespace

extern "C" void kernel_launch(void* const* d_in, const int* in_sizes, int n_in,
                              void* d_out, int out_size, void* d_ws, size_t ws_size,
                              hipStream_t stream) {
  const float* x  = (const float*)d_in[0];
  const float* wq = (const float*)d_in[1];
  const float* wk = (const float*)d_in[2];
  const float* wv = (const float*)d_in[3];
  const float* wr = (const float*)d_in[4];
  float* outp = (float*)d_out;
  (void)in_sizes; (void)n_in; (void)d_ws; (void)ws_size; (void)out_size;
  hipLaunchKernelGGL(interacting_layer_kernel, dim3(kB), dim3(256), 0, stream,
                     x, wq, wk, wv, wr, outp);
}

// Round 7
// 237.021 us; speedup vs baseline: 37.3662x; 31.7877x over previous
//
#include <hip/hip_runtime.h>
#include <math.h>

// InteractingLayer (AutoInt): B=4096, F=50, E=64, H=4, D=32.
// R7 = R6 with ONE fix: OFF_P 10400 -> 10496 (128-byte aligned).
// R6 failed (absmax 1.047) because the P buffer's XOR swizzle
// (addr ^ ((f&7)<<4)) is only a bijection when the row base is
// 128-aligned; 10400 = 81*128+32 lets g>=48 carry into bit 7 ->
// cross-row write collisions (e.g. P[1][48] and P[2][8] hit the
// same byte). 10496 = 82*128; P now spans [10496,18688) = up to OFF_X.
//
// Per head h:
//   stage Wt4[m][32n][64e] bf16 (transposed, XOR-swizzled) ; barrier
//   proj: X[64x64]bf16 @ W -> Q,K (LDS bf16 [64][64]), V^T (LDS [32][64]),
//         R kept in regs (2 x f32x4 per wave)                ; barrier
//   S = Q.K^T (K=32, 1 MFMA/tile) -> S[50][52] f32 LDS       ; barrier
//   softmax (4 lanes/row) -> P[64][64] bf16 (cols>=50 = 0)   ; barrier
//   O = P.V (K=64) + R -> relu -> store
// Fragment maps: A row = lane&15, k = 8*(lane>>4)+j (contig 8);
//   B col = lane&15, same k-map;  C/D col = lane&15, row = 4*(lane>>4)+reg
//   (identical k-map on A and B makes any k-permutation cancel in the dot).
// LDS 47360 B -> 3 blocks/CU.

namespace {

typedef __attribute__((ext_vector_type(8))) short bf16x8;   // 8 bf16
typedef __attribute__((ext_vector_type(4))) float f32x4;

__device__ __forceinline__ unsigned short f2bf(float f) {   // RNE f32->bf16
  unsigned int u = __float_as_uint(f);
  u += 0x7fffu + ((u >> 16) & 1u);
  return (unsigned short)(u >> 16);
}

// LDS byte map:
//  [0,18688): proj: Wt4[4][32][64]bf16 (16384B) | attn: S[50][52]f32 @0 (10400B),
//             P[64][64]bf16 @10496 (8192B, ends at 18688)
//  [18688,26880): Xbf [64][64] bf16, rows 50..63 zero
//  [26880,35072): Qh  [64][64] bf16 (cols 0..31 used)
//  [35072,43264): Kh  [64][64] bf16
//  [43264,47360): Vth [32][64] bf16 (row d, col f)
constexpr int OFF_WS = 0;
constexpr int OFF_S  = 0;
constexpr int OFF_P  = 10496;   // 82*128 — MUST be 128-aligned for the swizzle
constexpr int OFF_X  = 18688;
constexpr int OFF_Q  = 26880;
constexpr int OFF_K  = 35072;
constexpr int OFF_V  = 43264;
constexpr int LDS_BYTES = 47360;

__global__ __launch_bounds__(256, 2)
void autoint_kernel(const float* __restrict__ x,
                    const float* __restrict__ Wq,
                    const float* __restrict__ Wk,
                    const float* __restrict__ Wv,
                    const float* __restrict__ Wr,
                    float* __restrict__ out)
{
  __shared__ __align__(16) unsigned char SMEM[LDS_BYTES];

  const int tid = threadIdx.x;
  const int b   = blockIdx.x;
  const int l   = tid & 63;   // lane
  const int w   = tid >> 6;   // wave 0..3 = M-tile row
  const int c   = l & 15;
  const int g4  = l >> 4;

  // ---- stage X[b] as bf16 [64][64], swizzled; rows 50..63 zero ----
  {
    const float4* xg = reinterpret_cast<const float4*>(x + (size_t)b * (50 * 64));
    #pragma unroll
    for (int it = 0; it < 4; ++it) {
      int idx = tid + it * 256;
      if (idx < 800) {
        int f  = idx >> 4;
        int e4 = (idx & 15) << 2;
        float4 v = xg[idx];
        ushort4 hv;
        hv.x = f2bf(v.x); hv.y = f2bf(v.y); hv.z = f2bf(v.z); hv.w = f2bf(v.w);
        int byte = (OFF_X + f * 128 + 2 * e4) ^ ((f & 7) << 4);
        *reinterpret_cast<ushort4*>(&SMEM[byte]) = hv;
      }
    }
    if (tid < 224) {  // zero rows 50..63
      int f  = 50 + (tid >> 4);
      int e4 = (tid & 15) << 2;
      ushort4 z = {0, 0, 0, 0};
      int byte = (OFF_X + f * 128 + 2 * e4) ^ ((f & 7) << 4);
      *reinterpret_cast<ushort4*>(&SMEM[byte]) = z;
    }
  }

  bf16x8 a0, a1;  // X A-frags, rows 16w+c, k=e (loaded once at h==0)

  #pragma unroll
  for (int h = 0; h < 4; ++h) {
    __syncthreads();  // prev head's P/V reads done; (h==0: X staged)

    // ---- stage Wt4[m][n][e] bf16 for head h (transposed scatter) ----
    #pragma unroll
    for (int m = 0; m < 4; ++m) {
      const float* Wm = (m == 0) ? Wq : (m == 1) ? Wk : (m == 2) ? Wv : Wr;
      #pragma unroll
      for (int it = 0; it < 2; ++it) {
        int i  = tid + it * 256;       // 0..511
        int e  = i >> 3;               // 0..63
        int d4 = (i & 7) << 2;         // 0..28
        float4 v = *reinterpret_cast<const float4*>(Wm + e * 128 + 32 * h + d4);
        unsigned short hh[4] = {f2bf(v.x), f2bf(v.y), f2bf(v.z), f2bf(v.w)};
        #pragma unroll
        for (int k = 0; k < 4; ++k) {
          int n = d4 + k;
          int byte = (OFF_WS + m * 4096 + n * 128 + 2 * e) ^ ((n & 7) << 4);
          *reinterpret_cast<unsigned short*>(&SMEM[byte]) = hh[k];
        }
      }
    }
    __syncthreads();  // W staged

    if (h == 0) {  // load X A-frags once (Xbf visible after barrier)
      int row = 16 * w + c;
      int sw  = (row & 7) << 4;
      a0 = *reinterpret_cast<const bf16x8*>(&SMEM[(OFF_X + row * 128 + 16 * g4) ^ sw]);
      a1 = *reinterpret_cast<const bf16x8*>(&SMEM[(OFF_X + row * 128 + 64 + 16 * g4) ^ sw]);
    }

    // ---- projections: Q,K -> LDS; V -> Vth transposed; R -> regs ----
    f32x4 rRh[2];
    #pragma unroll
    for (int m = 0; m < 4; ++m) {
      #pragma unroll
      for (int tn = 0; tn < 2; ++tn) {
        int n  = 16 * tn + c;          // col within head, 0..31
        int bb = OFF_WS + m * 4096 + n * 128;
        int sw = (n & 7) << 4;
        bf16x8 b0 = *reinterpret_cast<const bf16x8*>(&SMEM[(bb + 16 * g4) ^ sw]);
        bf16x8 b1 = *reinterpret_cast<const bf16x8*>(&SMEM[(bb + 64 + 16 * g4) ^ sw]);
        f32x4 acc = {0.f, 0.f, 0.f, 0.f};
        acc = __builtin_amdgcn_mfma_f32_16x16x32_bf16(a0, b0, acc, 0, 0, 0);
        acc = __builtin_amdgcn_mfma_f32_16x16x32_bf16(a1, b1, acc, 0, 0, 0);
        if (m == 3) {
          rRh[tn] = acc;               // residual, consumed this head
        } else if (m == 2) {           // V: write transposed Vth[n][f]
          #pragma unroll
          for (int r = 0; r < 4; ++r) {
            int f = 16 * w + 4 * g4 + r;
            int byte = (OFF_V + n * 128 + 2 * f) ^ ((n & 7) << 4);
            *reinterpret_cast<unsigned short*>(&SMEM[byte]) = f2bf(acc[r]);
          }
        } else {                       // Q or K: [f][d] bf16
          int dst = (m == 0) ? OFF_Q : OFF_K;
          #pragma unroll
          for (int r = 0; r < 4; ++r) {
            int f = 16 * w + 4 * g4 + r;
            int byte = (dst + f * 128 + 2 * n) ^ ((f & 7) << 4);
            *reinterpret_cast<unsigned short*>(&SMEM[byte]) = f2bf(acc[r]);
          }
        }
      }
    }
    __syncthreads();  // Q,K,V ready; Wstage reads done (S overlays it)

    // ---- S = Q.K^T (M=64, N=64, K=32): wave w = M-row, 4 N-tiles ----
    {
      int rowq = 16 * w + c;
      int swq  = (rowq & 7) << 4;
      bf16x8 qa = *reinterpret_cast<const bf16x8*>(&SMEM[(OFF_Q + rowq * 128 + 16 * g4) ^ swq]);
      f32x4 sacc[4];
      #pragma unroll
      for (int tn = 0; tn < 4; ++tn) {
        int g   = 16 * tn + c;
        int swk = (g & 7) << 4;
        bf16x8 kf = *reinterpret_cast<const bf16x8*>(&SMEM[(OFF_K + g * 128 + 16 * g4) ^ swk]);
        f32x4 z = {0.f, 0.f, 0.f, 0.f};
        sacc[tn] = __builtin_amdgcn_mfma_f32_16x16x32_bf16(qa, kf, z, 0, 0, 0);
      }
      #pragma unroll
      for (int tn = 0; tn < 4; ++tn) {
        int g = 16 * tn + c;
        #pragma unroll
        for (int r = 0; r < 4; ++r) {
          int f = 16 * w + 4 * g4 + r;
          if (f < 50 && g < 50)
            *reinterpret_cast<float*>(&SMEM[OFF_S + (f * 52 + g) * 4]) = sacc[tn][r];
        }
      }
    }
    __syncthreads();  // S ready

    // ---- softmax rows f<50 (4 lanes/row), write P bf16 w/ zero pads ----
    if (tid < 200) {
      int f   = tid >> 2;
      int sub = tid & 3;
      const float* Srow = reinterpret_cast<const float*>(&SMEM[OFF_S]) + f * 52;
      float mx = -1e30f;
      #pragma unroll
      for (int j = 0; j < 13; ++j) {
        int g = sub + 4 * j;
        if (g < 50) mx = fmaxf(mx, Srow[g]);
      }
      mx = fmaxf(mx, __shfl_xor(mx, 1));
      mx = fmaxf(mx, __shfl_xor(mx, 2));
      float ev[13];
      float s = 0.f;
      #pragma unroll
      for (int j = 0; j < 13; ++j) {
        int g = sub + 4 * j;
        ev[j] = (g < 50) ? __expf(Srow[g] - mx) : 0.f;
        s += ev[j];
      }
      s += __shfl_xor(s, 1);
      s += __shfl_xor(s, 2);
      float inv = 1.f / s;
      #pragma unroll
      for (int j = 0; j < 16; ++j) {
        int g = sub + 4 * j;         // covers 0..63
        unsigned short pv = 0;
        if (j < 13) { if (g < 50) pv = f2bf(ev[j] * inv); }
        int byte = (OFF_P + f * 128 + 2 * g) ^ ((f & 7) << 4);
        *reinterpret_cast<unsigned short*>(&SMEM[byte]) = pv;
      }
    }
    __syncthreads();  // P ready

    // ---- O = P.V (K=64) + R -> relu -> store ----
    {
      int rp  = 16 * w + c;
      int swp = (rp & 7) << 4;
      bf16x8 pa0 = *reinterpret_cast<const bf16x8*>(&SMEM[(OFF_P + rp * 128 + 16 * g4) ^ swp]);
      bf16x8 pa1 = *reinterpret_cast<const bf16x8*>(&SMEM[(OFF_P + rp * 128 + 64 + 16 * g4) ^ swp]);
      #pragma unroll
      for (int tn = 0; tn < 2; ++tn) {
        int d   = 16 * tn + c;
        int swv = (d & 7) << 4;
        bf16x8 v0 = *reinterpret_cast<const bf16x8*>(&SMEM[(OFF_V + d * 128 + 16 * g4) ^ swv]);
        bf16x8 v1 = *reinterpret_cast<const bf16x8*>(&SMEM[(OFF_V + d * 128 + 64 + 16 * g4) ^ swv]);
        f32x4 o = {0.f, 0.f, 0.f, 0.f};
        o = __builtin_amdgcn_mfma_f32_16x16x32_bf16(pa0, v0, o, 0, 0, 0);
        o = __builtin_amdgcn_mfma_f32_16x16x32_bf16(pa1, v1, o, 0, 0, 0);
        f32x4 res = rRh[tn];
        #pragma unroll
        for (int r = 0; r < 4; ++r) {
          int f = 16 * w + 4 * g4 + r;
          if (f < 50)
            out[(size_t)b * 6400 + f * 128 + 32 * h + d] = fmaxf(o[r] + res[r], 0.f);
        }
      }
    }
  }
}

}  // namespace

extern "C" void kernel_launch(void* const* d_in, const int* in_sizes, int n_in,
                              void* d_out, int out_size, void* d_ws, size_t ws_size,
                              hipStream_t stream) {
  const float* x  = (const float*)d_in[0];
  const float* wq = (const float*)d_in[1];
  const float* wk = (const float*)d_in[2];
  const float* wv = (const float*)d_in[3];
  const float* wr = (const float*)d_in[4];
  float* outp = (float*)d_out;
  (void)in_sizes; (void)n_in; (void)d_ws; (void)ws_size; (void)out_size;
  hipLaunchKernelGGL(autoint_kernel, dim3(4096), dim3(256), 0, stream,
                     x, wq, wk, wv, wr, outp);
}